// Round 2
// baseline (180694.287 us; speedup 1.0000x reference)
//
#include <hip/hip_runtime.h>
#include <stdint.h>

// R2: register-resident weights (512 thr/block, 128 dw/thread, launch_bounds(512,2))
//     + per-CU flag words instead of shared atomicAdd counters; wave0-only polling.

#define S_LEN 8192
#define HID   1024
#define DIN0  256
#define NL    4
#define NCU_L 64        // CUs per layer
#define NTHR  512       // threads per block (8 waves)
#define NWAVE 8
#define SPL0  80        // weight dwords per lane per wave, layer 0 (8*80*2 = 1280 cols)
#define SPL   128       // layers 1-3 (8*128*2 = 2048 cols)

typedef _Float16 half2v __attribute__((ext_vector_type(2)));

#if defined(__has_builtin)
#if __has_builtin(__builtin_amdgcn_fdot2)
#define HAVE_FDOT2 1
#endif
#endif

__device__ __forceinline__ float dot2acc(uint32_t w, uint32_t x, float acc) {
#ifdef HAVE_FDOT2
    return __builtin_amdgcn_fdot2(__builtin_bit_cast(half2v, w),
                                  __builtin_bit_cast(half2v, x), acc, false);
#else
    half2v hw = __builtin_bit_cast(half2v, w);
    half2v hx = __builtin_bit_cast(half2v, x);
    return acc + (float)hw.x * (float)hx.x + (float)hw.y * (float)hx.y;
#endif
}

// ---- workspace layout (dwords/bytes) ----
constexpr size_t X0_DW  = (size_t)S_LEN * DIN0 / 2;                 // 1M dw = 4 MB
constexpr size_t X0B    = X0_DW * 4;
constexpr size_t HB     = (size_t)NL * S_LEN * HID * 2;             // 64 MB
constexpr size_t W0_DW  = (size_t)NCU_L * NWAVE * SPL0 * 64;        // 2.62M dw
constexpr size_t WL_DW  = (size_t)NCU_L * NWAVE * SPL * 64;         // 4.19M dw
constexpr size_t WB     = (W0_DW + 3 * WL_DW) * 4;                  // ~58 MB
constexpr size_t FLAG_N = (size_t)NL * NCU_L + 1;                   // +1 abort flag
constexpr size_t TOTAL_WS = X0B + HB + WB + FLAG_N * 4;

// ---------------- pre-kernels ----------------

__global__ void conv_x_kernel(const float* __restrict__ x, uint32_t* __restrict__ dst) {
    int i = blockIdx.x * 256 + threadIdx.x;   // exactly X0_DW threads
    float v0 = x[2 * i], v1 = x[2 * i + 1];
    half2v h = {(_Float16)v0, (_Float16)v1};
    dst[i] = __builtin_bit_cast(uint32_t, h);
}

// dst layout: [k(64)][wave(8)][c(SP)][lane(64)]; lane -> gate row, wave -> column slice
__global__ void pack_weights_kernel(const float* __restrict__ wih, const float* __restrict__ whh,
                                    int din, int SP, uint32_t* __restrict__ dst) {
    int i = blockIdx.x * 256 + threadIdx.x;   // exactly 64*8*SP*64 threads
    int r = i & 63;
    int q = i >> 6;
    int c = q % SP; q /= SP;
    int w = q & 7;
    int k = q >> 3;
    int row = (r >> 4) * HID + k * 16 + (r & 15);
    int col = w * (2 * SP) + 2 * c;           // half-index into [x(din) | h(HID)]
    float v0 = (col < din) ? wih[(size_t)row * din + col] : whh[(size_t)row * HID + (col - din)];
    float v1 = (col + 1 < din) ? wih[(size_t)row * din + col + 1] : whh[(size_t)row * HID + (col + 1 - din)];
    half2v h = {(_Float16)v0, (_Float16)v1};
    dst[i] = __builtin_bit_cast(uint32_t, h);
}

__global__ void init_misc_kernel(int* __restrict__ flags, int n, float* __restrict__ out,
                                 const float* __restrict__ fcb) {
    int i = blockIdx.x * 256 + threadIdx.x;
    if (i < n) flags[i] = 0;
    if (i == 0) out[0] = fcb[0];
}

// ---------------- persistent LSTM kernel ----------------

__device__ __forceinline__ float fsigmoid(float x) { return 1.f / (1.f + __expf(-x)); }
__device__ __forceinline__ float ftanh_c(float x) {   // input pre-clamped |x|<=15
    float e = __expf(-2.f * x);
    return (1.f - e) / (1.f + e);
}

template <int SP, int DIN>
__device__ __forceinline__ void run_layer(
    int k,
    const uint32_t* __restrict__ xsrc,   // packed fp16 pairs, row stride DIN/2 dwords
    _Float16* hh_own,                    // own-layer h history (half), row stride HID
    const uint32_t* hh_dw_own,           // dword view of same buffer
    const uint32_t* __restrict__ wsrc,   // this block's packed weights
    const float* __restrict__ bias,
    const float* __restrict__ fcw,
    float* out,
    int* ownf, int* upf, int* abortf, bool doFC)
{
    constexpr int XDW  = DIN / 2;            // staged x dwords
    constexpr int INDW = XDW + HID / 2;      // total staged dwords
    static_assert(INDW == NWAVE * SP, "layout");

    __shared__ alignas(16) uint32_t in_lds[INDW];
    __shared__ float red[NWAVE][64];

    const int tid  = threadIdx.x;
    const int wave = tid >> 6;
    const int lane = tid & 63;

    // ---- resident weight slice: SP dwords/thread in VGPRs ----
    uint32_t wreg[SP];
    {
        const uint32_t* wb = wsrc + (size_t)wave * SP * 64 + lane;
#pragma unroll
        for (int c = 0; c < SP; ++c) wreg[c] = wb[(size_t)c * 64];
    }

    float bval = 0.f, fcv = 0.f;
    if (wave == 0) {
        bval = bias[(lane >> 4) * HID + k * 16 + (lane & 15)];
        if (lane < 16) fcv = fcw[k * 16 + lane];
    }
    float cst = 0.f, hval = 0.f;

    for (int t = 0; t < S_LEN; ++t) {
        // ---- wave0 polls readiness flags; other waves park at barrier ----
        if (wave == 0) {
            int it = 0;
            for (;;) {
                int ok = 1;
                if (upf)
                    ok &= (__hip_atomic_load(upf + lane, __ATOMIC_RELAXED,
                                             __HIP_MEMORY_SCOPE_AGENT) >= t + 1);
                if (t)
                    ok &= (__hip_atomic_load(ownf + lane, __ATOMIC_RELAXED,
                                             __HIP_MEMORY_SCOPE_AGENT) >= t);
                if (__all(ok)) break;
                if ((++it & 63) == 0) {
                    if (__hip_atomic_load(abortf, __ATOMIC_RELAXED, __HIP_MEMORY_SCOPE_AGENT)) break;
                    if (it > (1 << 22)) {
                        __hip_atomic_store(abortf, 1, __ATOMIC_RELAXED, __HIP_MEMORY_SCOPE_AGENT);
                        break;
                    }
                }
            }
        }
        __syncthreads();
        __builtin_amdgcn_fence(__ATOMIC_ACQUIRE, "agent");  // all waves: invalidate before reads

        // ---- stage x_t || h_{t-1} into LDS (8B per thread) ----
        {
            const int dw = tid * 2;
            if (dw < XDW) {
                *(int2*)&in_lds[dw] = *(const int2*)&xsrc[(size_t)t * XDW + dw];
            } else if (dw < INDW) {
                int2 v = {0, 0};
                if (t) v = *(const int2*)&hh_dw_own[(size_t)(t - 1) * (HID / 2) + (dw - XDW)];
                *(int2*)&in_lds[dw] = v;
            }
        }
        __syncthreads();

        // ---- dot: lane = gate row, wave = column slice; x broadcast from LDS ----
        const uint32_t* wi = in_lds + wave * SP;
        float a0 = 0, a1 = 0, a2 = 0, a3 = 0, a4 = 0, a5 = 0, a6 = 0, a7 = 0;
#pragma unroll
        for (int c = 0; c < SP; c += 8) {
            a0 = dot2acc(wreg[c + 0], wi[c + 0], a0);
            a1 = dot2acc(wreg[c + 1], wi[c + 1], a1);
            a2 = dot2acc(wreg[c + 2], wi[c + 2], a2);
            a3 = dot2acc(wreg[c + 3], wi[c + 3], a3);
            a4 = dot2acc(wreg[c + 4], wi[c + 4], a4);
            a5 = dot2acc(wreg[c + 5], wi[c + 5], a5);
            a6 = dot2acc(wreg[c + 6], wi[c + 6], a6);
            a7 = dot2acc(wreg[c + 7], wi[c + 7], a7);
        }
        red[wave][lane] = ((a0 + a1) + (a2 + a3)) + ((a4 + a5) + (a6 + a7));
        __syncthreads();

        // ---- wave0: reduce, gates, state update, publish ----
        if (wave == 0) {
            float p = ((red[0][lane] + red[1][lane]) + (red[2][lane] + red[3][lane])) +
                      ((red[4][lane] + red[5][lane]) + (red[6][lane] + red[7][lane])) + bval;
            p = fminf(15.f, fmaxf(-15.f, p));
            const int j = lane & 15;
            float pi = __shfl(p, j);
            float pf = __shfl(p, j + 16);
            float pg = __shfl(p, j + 32);
            float po = __shfl(p, j + 48);
            if (lane < 16) {
                float ig = fsigmoid(pi);
                float fg = fsigmoid(pf);
                float gg = ftanh_c(pg);
                float og = fsigmoid(po);
                cst = fg * cst + ig * gg;
                float c2 = fminf(15.f, fmaxf(-15.f, cst));
                hval = og * ftanh_c(c2);
                hh_own[(size_t)t * HID + k * 16 + lane] = (_Float16)hval;
            }
            __builtin_amdgcn_fence(__ATOMIC_RELEASE, "agent");
            if (lane == 0)
                __hip_atomic_store(ownf + k, t + 1, __ATOMIC_RELAXED, __HIP_MEMORY_SCOPE_AGENT);
        }
    }

    // ---- final FC (layer 3): y = fc_w . h_last + fc_b ----
    if (doFC && wave == 0) {
        float p = (lane < 16) ? fcv * hval : 0.f;
#pragma unroll
        for (int o = 8; o; o >>= 1) p += __shfl_xor(p, o);
        if (lane == 0) atomicAdd(out, p);
    }
}

__global__ __launch_bounds__(NTHR, 2) void lstm_persistent(
    const uint32_t* __restrict__ x0p,
    _Float16* hh,
    const uint32_t* __restrict__ wp,
    const float* __restrict__ b0, const float* __restrict__ b1,
    const float* __restrict__ b2, const float* __restrict__ b3,
    const float* __restrict__ fcw, float* out,
    int* flags, int* abortf)
{
    const int bid = blockIdx.x;
    const int xcd = bid & 7;
    const int layer = xcd >> 1;                    // 2 XCDs per layer
    const int k = ((bid >> 3) << 1) | (xcd & 1);   // 0..63 within layer

    const float* bias = (layer == 0) ? b0 : (layer == 1) ? b1 : (layer == 2) ? b2 : b3;
    int* ownf = flags + layer * NCU_L;
    int* upf  = layer ? (flags + (layer - 1) * NCU_L) : nullptr;

    _Float16* hh_own = hh + (size_t)layer * S_LEN * HID;
    const uint32_t* hh_dw_own = (const uint32_t*)hh + (size_t)layer * S_LEN * (HID / 2);

    if (layer == 0) {
        const uint32_t* wsrc = wp + (size_t)k * NWAVE * SPL0 * 64;
        run_layer<SPL0, DIN0>(k, x0p, hh_own, hh_dw_own, wsrc, bias, fcw, out,
                              ownf, nullptr, abortf, false);
    } else {
        const uint32_t* xsrc = (const uint32_t*)hh + (size_t)(layer - 1) * S_LEN * (HID / 2);
        const uint32_t* wsrc = wp + W0_DW + (size_t)(layer - 1) * WL_DW + (size_t)k * NWAVE * SPL * 64;
        run_layer<SPL, HID>(k, xsrc, hh_own, hh_dw_own, wsrc, bias, fcw, out,
                            ownf, upf, abortf, layer == 3);
    }
}

// ---------------- host launcher ----------------

extern "C" void kernel_launch(void* const* d_in, const int* in_sizes, int n_in,
                              void* d_out, int out_size, void* d_ws, size_t ws_size,
                              hipStream_t stream) {
    const float* seq  = (const float*)d_in[0];
    const float* wih0 = (const float*)d_in[1];
    const float* whh0 = (const float*)d_in[2];
    const float* b0   = (const float*)d_in[3];
    const float* wih1 = (const float*)d_in[4];
    const float* whh1 = (const float*)d_in[5];
    const float* b1   = (const float*)d_in[6];
    const float* wih2 = (const float*)d_in[7];
    const float* whh2 = (const float*)d_in[8];
    const float* b2   = (const float*)d_in[9];
    const float* wih3 = (const float*)d_in[10];
    const float* whh3 = (const float*)d_in[11];
    const float* b3   = (const float*)d_in[12];
    const float* fcw  = (const float*)d_in[13];
    const float* fcb  = (const float*)d_in[14];
    float* out = (float*)d_out;

    if (ws_size < TOTAL_WS) return;

    uint8_t* ws = (uint8_t*)d_ws;
    uint32_t* x0p = (uint32_t*)ws;
    _Float16* hh  = (_Float16*)(ws + X0B);
    uint32_t* wp  = (uint32_t*)(ws + X0B + HB);
    int* flags    = (int*)(ws + X0B + HB + WB);
    int* abortf   = flags + NL * NCU_L;

    conv_x_kernel<<<(int)(X0_DW / 256), 256, 0, stream>>>(seq, x0p);
    pack_weights_kernel<<<(int)(W0_DW / 256), 256, 0, stream>>>(wih0, whh0, DIN0, SPL0, wp);
    pack_weights_kernel<<<(int)(WL_DW / 256), 256, 0, stream>>>(wih1, whh1, HID, SPL, wp + W0_DW);
    pack_weights_kernel<<<(int)(WL_DW / 256), 256, 0, stream>>>(wih2, whh2, HID, SPL, wp + W0_DW + WL_DW);
    pack_weights_kernel<<<(int)(WL_DW / 256), 256, 0, stream>>>(wih3, whh3, HID, SPL, wp + W0_DW + 2 * WL_DW);
    init_misc_kernel<<<(int)((FLAG_N + 255) / 256), 256, 0, stream>>>(flags, (int)FLAG_N, out, fcb);

    // persistent pipelined recurrence: 256 blocks (1/CU), 512 threads
    lstm_persistent<<<256, NTHR, 0, stream>>>(x0p, hh, wp, b0, b1, b2, b3, fcw, out, flags, abortf);
}

// Round 3
// 176598.157 us; speedup vs baseline: 1.0232x; 1.0232x over previous
//
#include <hip/hip_runtime.h>
#include <stdint.h>

// R3: force weight residency in VGPRs via ext_vector_type(4) values + inline-asm
//     pins ("+v") so regalloc cannot rematerialize/demote them. Per-thread
//     contiguous 16B weight chunks -> one-time global_load_dwordx4.

#define S_LEN 8192
#define HID   1024
#define DIN0  256
#define NL    4
#define NCU_L 64        // CUs per layer
#define NTHR  512       // threads per block (8 waves)
#define NWAVE 8
#define SPL0  80        // weight dwords per lane per wave, layer 0 (8*80*2 = 1280 cols)
#define SPL   128       // layers 1-3 (8*128*2 = 2048 cols)

typedef _Float16 half2v __attribute__((ext_vector_type(2)));
typedef uint32_t v4u   __attribute__((ext_vector_type(4)));

#if defined(__has_builtin)
#if __has_builtin(__builtin_amdgcn_fdot2)
#define HAVE_FDOT2 1
#endif
#endif

__device__ __forceinline__ float dot2acc(uint32_t w, uint32_t x, float acc) {
#ifdef HAVE_FDOT2
    return __builtin_amdgcn_fdot2(__builtin_bit_cast(half2v, w),
                                  __builtin_bit_cast(half2v, x), acc, false);
#else
    half2v hw = __builtin_bit_cast(half2v, w);
    half2v hx = __builtin_bit_cast(half2v, x);
    return acc + (float)hw.x * (float)hx.x + (float)hw.y * (float)hx.y;
#endif
}

// ---- workspace layout (dwords/bytes) ----
constexpr size_t X0_DW  = (size_t)S_LEN * DIN0 / 2;                 // 4 MB
constexpr size_t X0B    = X0_DW * 4;
constexpr size_t HB     = (size_t)NL * S_LEN * HID * 2;             // 64 MB
constexpr size_t W0_DW  = (size_t)NCU_L * NWAVE * SPL0 * 64;
constexpr size_t WL_DW  = (size_t)NCU_L * NWAVE * SPL * 64;
constexpr size_t WB     = (W0_DW + 3 * WL_DW) * 4;                  // ~58 MB
constexpr size_t FLAG_N = (size_t)NL * NCU_L + 1;                   // +1 abort flag
constexpr size_t TOTAL_WS = X0B + HB + WB + FLAG_N * 4;

// ---------------- pre-kernels ----------------

__global__ void conv_x_kernel(const float* __restrict__ x, uint32_t* __restrict__ dst) {
    int i = blockIdx.x * 256 + threadIdx.x;   // exactly X0_DW threads
    float v0 = x[2 * i], v1 = x[2 * i + 1];
    half2v h = {(_Float16)v0, (_Float16)v1};
    dst[i] = __builtin_bit_cast(uint32_t, h);
}

// dst layout: [k(64)][wave(8)][c4(SP/4)][lane(64)][e(4)] — per-thread 16B chunks.
__global__ void pack_weights_kernel(const float* __restrict__ wih, const float* __restrict__ whh,
                                    int din, int SP, uint32_t* __restrict__ dst) {
    int i = blockIdx.x * 256 + threadIdx.x;   // exactly 64*8*SP*64 threads
    const int SP4 = SP / 4;
    int e = i & 3;
    int q = i >> 2;
    int l = q & 63; q >>= 6;
    int c4 = q % SP4; q /= SP4;
    int w = q & 7;
    int k = q >> 3;
    int c = c4 * 4 + e;                        // dword index within this wave's slice
    int row = (l >> 4) * HID + k * 16 + (l & 15);
    int col = w * (2 * SP) + 2 * c;            // half-index into [x(din) | h(HID)]
    float v0 = (col < din) ? wih[(size_t)row * din + col] : whh[(size_t)row * HID + (col - din)];
    float v1 = (col + 1 < din) ? wih[(size_t)row * din + col + 1] : whh[(size_t)row * HID + (col + 1 - din)];
    half2v h = {(_Float16)v0, (_Float16)v1};
    dst[i] = __builtin_bit_cast(uint32_t, h);
}

__global__ void init_misc_kernel(int* __restrict__ flags, int n, float* __restrict__ out,
                                 const float* __restrict__ fcb) {
    int i = blockIdx.x * 256 + threadIdx.x;
    if (i < n) flags[i] = 0;
    if (i == 0) out[0] = fcb[0];
}

// ---------------- persistent LSTM kernel ----------------

__device__ __forceinline__ float fsigmoid(float x) { return 1.f / (1.f + __expf(-x)); }
__device__ __forceinline__ float ftanh_c(float x) {   // input pre-clamped |x|<=15
    float e = __expf(-2.f * x);
    return (1.f - e) / (1.f + e);
}

template <int SP, int DIN>
__device__ __forceinline__ void run_layer(
    int k,
    const uint32_t* __restrict__ xsrc,   // packed fp16 pairs, row stride DIN/2 dwords
    _Float16* hh_own,                    // own-layer h history (half), row stride HID
    const uint32_t* hh_dw_own,           // dword view of same buffer
    const uint32_t* __restrict__ wsrc,   // this block's packed weights
    const float* __restrict__ bias,
    const float* __restrict__ fcw,
    float* out,
    int* ownf, int* upf, int* abortf, bool doFC)
{
    constexpr int SP4  = SP / 4;
    constexpr int XDW  = DIN / 2;            // staged x dwords
    constexpr int INDW = XDW + HID / 2;      // total staged dwords
    static_assert(INDW == NWAVE * SP, "layout");

    __shared__ alignas(16) uint32_t in_lds[INDW];
    __shared__ float red[NWAVE][64];

    const int tid  = threadIdx.x;
    const int wave = tid >> 6;
    const int lane = tid & 63;

    // ---- resident weight slice: SP dwords/thread as SP/4 vector values ----
    v4u wv[SP4];
    {
        const uint32_t* wb = wsrc + (size_t)wave * SP * 64 + lane * 4;
#pragma unroll
        for (int c4 = 0; c4 < SP4; ++c4)
            wv[c4] = *(const v4u*)(wb + (size_t)c4 * 256);
    }
    // Pin: asm-defined values are non-rematerializable; regalloc must keep
    // them in VGPR quads for the whole kernel.
#pragma unroll
    for (int c4 = 0; c4 < SP4; ++c4)
        asm volatile("" : "+v"(wv[c4]));

    float bval = 0.f, fcv = 0.f;
    if (wave == 0) {
        bval = bias[(lane >> 4) * HID + k * 16 + (lane & 15)];
        if (lane < 16) fcv = fcw[k * 16 + lane];
    }
    float cst = 0.f, hval = 0.f;

    for (int t = 0; t < S_LEN; ++t) {
        // ---- wave0 polls readiness flags; other waves park at barrier ----
        if (wave == 0) {
            int it = 0;
            for (;;) {
                int ok = 1;
                if (upf)
                    ok &= (__hip_atomic_load(upf + lane, __ATOMIC_RELAXED,
                                             __HIP_MEMORY_SCOPE_AGENT) >= t + 1);
                if (t)
                    ok &= (__hip_atomic_load(ownf + lane, __ATOMIC_RELAXED,
                                             __HIP_MEMORY_SCOPE_AGENT) >= t);
                if (__all(ok)) break;
                if ((++it & 63) == 0) {
                    if (__hip_atomic_load(abortf, __ATOMIC_RELAXED, __HIP_MEMORY_SCOPE_AGENT)) break;
                    if (it > (1 << 22)) {
                        __hip_atomic_store(abortf, 1, __ATOMIC_RELAXED, __HIP_MEMORY_SCOPE_AGENT);
                        break;
                    }
                }
            }
        }
        __syncthreads();
        __builtin_amdgcn_fence(__ATOMIC_ACQUIRE, "agent");

        // ---- stage x_t || h_{t-1} into LDS (8B per thread) ----
        {
            const int dw = tid * 2;
            if (dw < XDW) {
                *(int2*)&in_lds[dw] = *(const int2*)&xsrc[(size_t)t * XDW + dw];
            } else if (dw < INDW) {
                int2 v = {0, 0};
                if (t) v = *(const int2*)&hh_dw_own[(size_t)(t - 1) * (HID / 2) + (dw - XDW)];
                *(int2*)&in_lds[dw] = v;
            }
        }
        __syncthreads();

        // ---- dot: lane = gate row, wave = column slice; x broadcast from LDS ----
        const uint32_t* wi = in_lds + wave * SP;
        float a0 = 0, a1 = 0, a2 = 0, a3 = 0, a4 = 0, a5 = 0, a6 = 0, a7 = 0;
#pragma unroll
        for (int c4 = 0; c4 < SP4; c4 += 2) {
            v4u x0 = *(const v4u*)&wi[c4 * 4];
            v4u x1 = *(const v4u*)&wi[c4 * 4 + 4];
            a0 = dot2acc(wv[c4][0], x0[0], a0);
            a1 = dot2acc(wv[c4][1], x0[1], a1);
            a2 = dot2acc(wv[c4][2], x0[2], a2);
            a3 = dot2acc(wv[c4][3], x0[3], a3);
            a4 = dot2acc(wv[c4 + 1][0], x1[0], a4);
            a5 = dot2acc(wv[c4 + 1][1], x1[1], a5);
            a6 = dot2acc(wv[c4 + 1][2], x1[2], a6);
            a7 = dot2acc(wv[c4 + 1][3], x1[3], a7);
        }
        red[wave][lane] = ((a0 + a1) + (a2 + a3)) + ((a4 + a5) + (a6 + a7));
        __syncthreads();

        // ---- wave0: reduce, gates, state update, publish ----
        if (wave == 0) {
            float p = ((red[0][lane] + red[1][lane]) + (red[2][lane] + red[3][lane])) +
                      ((red[4][lane] + red[5][lane]) + (red[6][lane] + red[7][lane])) + bval;
            p = fminf(15.f, fmaxf(-15.f, p));
            const int j = lane & 15;
            float pi = __shfl(p, j);
            float pf = __shfl(p, j + 16);
            float pg = __shfl(p, j + 32);
            float po = __shfl(p, j + 48);
            if (lane < 16) {
                float ig = fsigmoid(pi);
                float fg = fsigmoid(pf);
                float gg = ftanh_c(pg);
                float og = fsigmoid(po);
                cst = fg * cst + ig * gg;
                float c2 = fminf(15.f, fmaxf(-15.f, cst));
                hval = og * ftanh_c(c2);
                hh_own[(size_t)t * HID + k * 16 + lane] = (_Float16)hval;
            }
            __builtin_amdgcn_fence(__ATOMIC_RELEASE, "agent");
            if (lane == 0)
                __hip_atomic_store(ownf + k, t + 1, __ATOMIC_RELAXED, __HIP_MEMORY_SCOPE_AGENT);
        }
    }

    // ---- final FC (layer 3): y = fc_w . h_last + fc_b ----
    if (doFC && wave == 0) {
        float p = (lane < 16) ? fcv * hval : 0.f;
#pragma unroll
        for (int o = 8; o; o >>= 1) p += __shfl_xor(p, o);
        if (lane == 0) atomicAdd(out, p);
    }
}

__global__ __launch_bounds__(NTHR, 2) void lstm_persistent(
    const uint32_t* __restrict__ x0p,
    _Float16* hh,
    const uint32_t* __restrict__ wp,
    const float* __restrict__ b0, const float* __restrict__ b1,
    const float* __restrict__ b2, const float* __restrict__ b3,
    const float* __restrict__ fcw, float* out,
    int* flags, int* abortf)
{
    const int bid = blockIdx.x;
    const int xcd = bid & 7;
    const int layer = xcd >> 1;                    // 2 XCDs per layer
    const int k = ((bid >> 3) << 1) | (xcd & 1);   // 0..63 within layer

    const float* bias = (layer == 0) ? b0 : (layer == 1) ? b1 : (layer == 2) ? b2 : b3;
    int* ownf = flags + layer * NCU_L;
    int* upf  = layer ? (flags + (layer - 1) * NCU_L) : nullptr;

    _Float16* hh_own = hh + (size_t)layer * S_LEN * HID;
    const uint32_t* hh_dw_own = (const uint32_t*)hh + (size_t)layer * S_LEN * (HID / 2);

    if (layer == 0) {
        const uint32_t* wsrc = wp + (size_t)k * NWAVE * SPL0 * 64;
        run_layer<SPL0, DIN0>(k, x0p, hh_own, hh_dw_own, wsrc, bias, fcw, out,
                              ownf, nullptr, abortf, false);
    } else {
        const uint32_t* xsrc = (const uint32_t*)hh + (size_t)(layer - 1) * S_LEN * (HID / 2);
        const uint32_t* wsrc = wp + W0_DW + (size_t)(layer - 1) * WL_DW + (size_t)k * NWAVE * SPL * 64;
        run_layer<SPL, HID>(k, xsrc, hh_own, hh_dw_own, wsrc, bias, fcw, out,
                            ownf, upf, abortf, layer == 3);
    }
}

// ---------------- host launcher ----------------

extern "C" void kernel_launch(void* const* d_in, const int* in_sizes, int n_in,
                              void* d_out, int out_size, void* d_ws, size_t ws_size,
                              hipStream_t stream) {
    const float* seq  = (const float*)d_in[0];
    const float* wih0 = (const float*)d_in[1];
    const float* whh0 = (const float*)d_in[2];
    const float* b0   = (const float*)d_in[3];
    const float* wih1 = (const float*)d_in[4];
    const float* whh1 = (const float*)d_in[5];
    const float* b1   = (const float*)d_in[6];
    const float* wih2 = (const float*)d_in[7];
    const float* whh2 = (const float*)d_in[8];
    const float* b2   = (const float*)d_in[9];
    const float* wih3 = (const float*)d_in[10];
    const float* whh3 = (const float*)d_in[11];
    const float* b3   = (const float*)d_in[12];
    const float* fcw  = (const float*)d_in[13];
    const float* fcb  = (const float*)d_in[14];
    float* out = (float*)d_out;

    if (ws_size < TOTAL_WS) return;

    uint8_t* ws = (uint8_t*)d_ws;
    uint32_t* x0p = (uint32_t*)ws;
    _Float16* hh  = (_Float16*)(ws + X0B);
    uint32_t* wp  = (uint32_t*)(ws + X0B + HB);
    int* flags    = (int*)(ws + X0B + HB + WB);
    int* abortf   = flags + NL * NCU_L;

    conv_x_kernel<<<(int)(X0_DW / 256), 256, 0, stream>>>(seq, x0p);
    pack_weights_kernel<<<(int)(W0_DW / 256), 256, 0, stream>>>(wih0, whh0, DIN0, SPL0, wp);
    pack_weights_kernel<<<(int)(WL_DW / 256), 256, 0, stream>>>(wih1, whh1, HID, SPL, wp + W0_DW);
    pack_weights_kernel<<<(int)(WL_DW / 256), 256, 0, stream>>>(wih2, whh2, HID, SPL, wp + W0_DW + WL_DW);
    pack_weights_kernel<<<(int)(WL_DW / 256), 256, 0, stream>>>(wih3, whh3, HID, SPL, wp + W0_DW + 2 * WL_DW);
    init_misc_kernel<<<(int)((FLAG_N + 255) / 256), 256, 0, stream>>>(flags, (int)FLAG_N, out, fcb);

    // persistent pipelined recurrence: 256 blocks (1/CU), 512 threads
    lstm_persistent<<<256, NTHR, 0, stream>>>(x0p, hh, wp, b0, b1, b2, b3, fcw, out, flags, abortf);
}